// Round 1
// baseline (2388.367 us; speedup 1.0000x reference)
//
#include <hip/hip_runtime.h>

// ---------------------------------------------------------------------------
// GAT (heads=1) x2 layers x2 branches + FC head, fp32.
// Softmax over incoming edges done WITHOUT the max pass (shift-invariant;
// self-loops guarantee nonempty segments; |logits| <~ 10 so expf is safe).
// ---------------------------------------------------------------------------

#define NNODES 50000

// C[M,128] = (relu_in? relu(A) : A)[M,K] @ W[K,128] (+ bias)
__global__ __launch_bounds__(256) void gemm_k(
    const float* __restrict__ A, const float* __restrict__ W,
    const float* __restrict__ bias, float* __restrict__ C,
    int M, int K, int relu_in)
{
  __shared__ float As[64][33];   // +1 pad: avoid bank conflicts on column reads
  __shared__ float Ws[32][128];
  const int tid = threadIdx.x;
  const int bm  = blockIdx.x * 64;
  const int tc  = tid & 15;     // 16 col-groups of 8
  const int tr  = tid >> 4;     // 16 row-groups of 4
  float acc[4][8];
#pragma unroll
  for (int r = 0; r < 4; ++r)
#pragma unroll
    for (int c = 0; c < 8; ++c) acc[r][c] = 0.f;

  for (int k0 = 0; k0 < K; k0 += 32) {
    // A tile 64x32 (2048 floats, 2 x float4 per thread)
#pragma unroll
    for (int t = 0; t < 2; ++t) {
      int v   = tid + t * 256;
      int row = v >> 3;
      int kq  = (v & 7) * 4;
      float4 av = make_float4(0.f, 0.f, 0.f, 0.f);
      if (bm + row < M)
        av = *reinterpret_cast<const float4*>(A + (size_t)(bm + row) * K + k0 + kq);
      if (relu_in) {
        av.x = fmaxf(av.x, 0.f); av.y = fmaxf(av.y, 0.f);
        av.z = fmaxf(av.z, 0.f); av.w = fmaxf(av.w, 0.f);
      }
      As[row][kq + 0] = av.x; As[row][kq + 1] = av.y;
      As[row][kq + 2] = av.z; As[row][kq + 3] = av.w;
    }
    // W tile 32x128 (4096 floats, 4 x float4 per thread)
#pragma unroll
    for (int t = 0; t < 4; ++t) {
      int v  = tid + t * 256;
      int kr = v >> 5;
      int nq = (v & 31) * 4;
      *reinterpret_cast<float4*>(&Ws[kr][nq]) =
          *reinterpret_cast<const float4*>(W + (size_t)(k0 + kr) * 128 + nq);
    }
    __syncthreads();
#pragma unroll
    for (int kk = 0; kk < 32; ++kk) {
      float a[4];
#pragma unroll
      for (int r = 0; r < 4; ++r) a[r] = As[tr * 4 + r][kk];
      float4 w0 = *reinterpret_cast<const float4*>(&Ws[kk][tc * 8]);
      float4 w1 = *reinterpret_cast<const float4*>(&Ws[kk][tc * 8 + 4]);
      float w[8] = {w0.x, w0.y, w0.z, w0.w, w1.x, w1.y, w1.z, w1.w};
#pragma unroll
      for (int r = 0; r < 4; ++r)
#pragma unroll
        for (int c = 0; c < 8; ++c) acc[r][c] += a[r] * w[c];
    }
    __syncthreads();
  }
#pragma unroll
  for (int r = 0; r < 4; ++r) {
    int row = bm + tr * 4 + r;
    if (row >= M) continue;
    float b0 = 0.f, b1 = 0.f, b2 = 0.f, b3 = 0.f, b4 = 0.f, b5 = 0.f, b6 = 0.f, b7 = 0.f;
    if (bias) {
      b0 = bias[tc * 8 + 0]; b1 = bias[tc * 8 + 1]; b2 = bias[tc * 8 + 2]; b3 = bias[tc * 8 + 3];
      b4 = bias[tc * 8 + 4]; b5 = bias[tc * 8 + 5]; b6 = bias[tc * 8 + 6]; b7 = bias[tc * 8 + 7];
    }
    float4 o0 = make_float4(acc[r][0] + b0, acc[r][1] + b1, acc[r][2] + b2, acc[r][3] + b3);
    float4 o1 = make_float4(acc[r][4] + b4, acc[r][5] + b5, acc[r][6] + b6, acc[r][7] + b7);
    *reinterpret_cast<float4*>(C + (size_t)row * 128 + tc * 8)     = o0;
    *reinterpret_cast<float4*>(C + (size_t)row * 128 + tc * 8 + 4) = o1;
  }
}

// es[i] = h[i,:]·a_src ; ed[i] = h[i,:]·a_dst    (one wave per node)
__global__ __launch_bounds__(256) void attn_k(
    const float* __restrict__ h, const float* __restrict__ a_s,
    const float* __restrict__ a_d, float* __restrict__ es, float* __restrict__ ed, int N)
{
  int wave = (blockIdx.x * 256 + threadIdx.x) >> 6;
  int lane = threadIdx.x & 63;
  if (wave >= N) return;
  const float* hr = h + (size_t)wave * 128;
  float h0 = hr[lane], h1 = hr[lane + 64];
  float s = h0 * a_s[lane] + h1 * a_s[lane + 64];
  float d = h0 * a_d[lane] + h1 * a_d[lane + 64];
#pragma unroll
  for (int off = 32; off > 0; off >>= 1) {
    s += __shfl_down(s, off, 64);
    d += __shfl_down(d, off, 64);
  }
  if (lane == 0) { es[wave] = s; ed[wave] = d; }
}

// p[e] = exp(leakyrelu(es[src]+ed[dst])); denom[dst] += p.  e in [E, E+N) = self loops.
__global__ __launch_bounds__(256) void edge_p_k(
    const int* __restrict__ src, const int* __restrict__ dst,
    const float* __restrict__ es, const float* __restrict__ ed,
    float* __restrict__ p, float* __restrict__ denom, int E, int N)
{
  int e = blockIdx.x * 256 + threadIdx.x;
  if (e >= E + N) return;
  int s, d;
  if (e < E) { s = src[e]; d = dst[e]; } else { s = d = e - E; }
  float l = es[s] + ed[d];
  l = (l > 0.f) ? l : 0.2f * l;
  float pe = expf(l);
  p[e] = pe;
  atomicAdd(&denom[d], pe);
}

// out[i,c] = (p_self[i]/denom[i]) * h[i,c] + bias[c]
__global__ __launch_bounds__(256) void self_init_k(
    const float* __restrict__ h, const float* __restrict__ p,
    const float* __restrict__ denom, const float* __restrict__ bias,
    float* __restrict__ out, int N, int E)
{
  int t = blockIdx.x * 256 + threadIdx.x;
  if (t >= N * 128) return;
  int i = t >> 7, c = t & 127;
  float alpha = p[E + i] / denom[i];
  out[t] = alpha * h[(size_t)i * 128 + c] + bias[c];
}

// out[dst,:] += (p[e]/denom[dst]) * h[src,:]   (one wave per edge, 2 floats/lane)
__global__ __launch_bounds__(256) void edge_aggr_k(
    const int* __restrict__ src, const int* __restrict__ dst,
    const float* __restrict__ p, const float* __restrict__ denom,
    const float* __restrict__ h, float* __restrict__ out, int E)
{
  int w    = (blockIdx.x * 256 + threadIdx.x) >> 6;
  int lane = threadIdx.x & 63;
  if (w >= E) return;
  int s = src[w], d = dst[w];
  float alpha = p[w] / denom[d];
  float2 hv = *reinterpret_cast<const float2*>(h + (size_t)s * 128 + lane * 2);
  atomicAdd(out + (size_t)d * 128 + lane * 2,     alpha * hv.x);
  atomicAdd(out + (size_t)d * 128 + lane * 2 + 1, alpha * hv.y);
}

// fcbuf[i, 0:128] = relu(hx[idx[i]]), [128:256] = relu(hy[idx[i]])
__global__ __launch_bounds__(256) void gather_k(
    const int* __restrict__ idx, const float* __restrict__ hx,
    const float* __restrict__ hy, float* __restrict__ outb, int M)
{
  int t = blockIdx.x * 256 + threadIdx.x;
  if (t >= M * 256) return;
  int i = t >> 8, c = t & 255;
  int r = idx[i];
  float v = (c < 128) ? hx[(size_t)r * 128 + c] : hy[(size_t)r * 128 + (c - 128)];
  outb[t] = fmaxf(v, 0.f);
}

// out[i, 0:64] = relu(fc[i,:]) @ Wout[128,64] + bout   (one wave per row)
__global__ __launch_bounds__(256) void head_k(
    const float* __restrict__ fc, const float* __restrict__ Wout,
    const float* __restrict__ bout, float* __restrict__ out, int M)
{
  __shared__ float rowbuf[4][128];
  int widx = threadIdx.x >> 6;
  int lane = threadIdx.x & 63;
  int i = blockIdx.x * 4 + widx;
  if (i >= M) return;
  const float* fr = fc + (size_t)i * 128;
  rowbuf[widx][lane]      = fmaxf(fr[lane], 0.f);
  rowbuf[widx][lane + 64] = fmaxf(fr[lane + 64], 0.f);
  // same-wave LDS write->read: in-order per wave, no barrier needed
  float acc = bout[lane];
#pragma unroll 8
  for (int k = 0; k < 128; ++k) acc += rowbuf[widx][k] * Wout[k * 64 + lane];
  out[(size_t)i * 64 + lane] = acc;
}

static void run_gat_layer(const float* in, int relu_in, const float* W,
                          const float* a_s, const float* a_d, const float* b,
                          const int* src, const int* dst, int E, int N,
                          float* h, float* es, float* ed, float* denom, float* pbuf,
                          float* out, hipStream_t stream)
{
  gemm_k<<<dim3((N + 63) / 64), 256, 0, stream>>>(in, W, nullptr, h, N, 128, relu_in);
  attn_k<<<dim3((N + 3) / 4), 256, 0, stream>>>(h, a_s, a_d, es, ed, N);
  hipMemsetAsync(denom, 0, (size_t)N * 4, stream);
  edge_p_k<<<dim3((E + N + 255) / 256), 256, 0, stream>>>(src, dst, es, ed, pbuf, denom, E, N);
  self_init_k<<<dim3((N * 128 + 255) / 256), 256, 0, stream>>>(h, pbuf, denom, b, out, N, E);
  edge_aggr_k<<<dim3((E + 3) / 4), 256, 0, stream>>>(src, dst, pbuf, denom, h, out, E);
}

extern "C" void kernel_launch(void* const* d_in, const int* in_sizes, int n_in,
                              void* d_out, int out_size, void* d_ws, size_t ws_size,
                              hipStream_t stream)
{
  const float* x    = (const float*)d_in[0];
  const int*   eix  = (const int*)d_in[1];
  const int*   eiy  = (const int*)d_in[2];
  const int*   idx  = (const int*)d_in[3];
  const float* Wx1  = (const float*)d_in[4];
  const float* asx1 = (const float*)d_in[5];
  const float* adx1 = (const float*)d_in[6];
  const float* bx1  = (const float*)d_in[7];
  const float* Wx2  = (const float*)d_in[8];
  const float* asx2 = (const float*)d_in[9];
  const float* adx2 = (const float*)d_in[10];
  const float* bx2  = (const float*)d_in[11];
  const float* Wy1  = (const float*)d_in[12];
  const float* asy1 = (const float*)d_in[13];
  const float* ady1 = (const float*)d_in[14];
  const float* by1  = (const float*)d_in[15];
  const float* Wy2  = (const float*)d_in[16];
  const float* asy2 = (const float*)d_in[17];
  const float* ady2 = (const float*)d_in[18];
  const float* by2  = (const float*)d_in[19];
  const float* Wfc  = (const float*)d_in[20];
  const float* bfc  = (const float*)d_in[21];
  const float* Wout = (const float*)d_in[22];
  const float* bout = (const float*)d_in[23];

  const int N    = in_sizes[0] / 128;   // 50000
  const int E    = in_sizes[1] / 2;     // 600000
  const int Midx = in_sizes[3];         // 10000

  const int* srcx = eix;
  const int* dstx = eix + E;
  const int* srcy = eiy;
  const int* dsty = eiy + E;

  // workspace layout (fp32)
  char* wsb = (char*)d_ws;
  const size_t NB = (size_t)N * 128 * 4;    // 25.6 MB
  float* hbuf  = (float*)(wsb);
  float* inter = (float*)(wsb + NB);
  float* hx    = (float*)(wsb + 2 * NB);
  float* hy    = (float*)(wsb + 3 * NB);
  char*  small = wsb + 4 * NB;
  float* es    = (float*)(small);
  float* ed    = (float*)(small + (size_t)N * 4);
  float* denom = (float*)(small + (size_t)N * 8);
  float* pbuf  = (float*)(small + (size_t)N * 12);   // (E+N) floats

  // x branch
  run_gat_layer(x,     0, Wx1, asx1, adx1, bx1, srcx, dstx, E, N, hbuf, es, ed, denom, pbuf, inter, stream);
  run_gat_layer(inter, 1, Wx2, asx2, adx2, bx2, srcx, dstx, E, N, hbuf, es, ed, denom, pbuf, hx,    stream);
  // y branch
  run_gat_layer(x,     0, Wy1, asy1, ady1, by1, srcy, dsty, E, N, hbuf, es, ed, denom, pbuf, inter, stream);
  run_gat_layer(inter, 1, Wy2, asy2, ady2, by2, srcy, dsty, E, N, hbuf, es, ed, denom, pbuf, hy,    stream);

  // head: only the 10000 indexed rows
  float* fcbuf = hbuf;            // 10000 x 256 (reuse)
  float* fcout = inter;           // 10000 x 128 (reuse)
  gather_k<<<dim3((Midx * 256 + 255) / 256), 256, 0, stream>>>(idx, hx, hy, fcbuf, Midx);
  gemm_k<<<dim3((Midx + 63) / 64), 256, 0, stream>>>(fcbuf, Wfc, bfc, fcout, Midx, 256, 0);
  head_k<<<dim3((Midx + 3) / 4), 256, 0, stream>>>(fcout, Wout, bout, (float*)d_out, Midx);
}

// Round 2
// 666.210 us; speedup vs baseline: 3.5850x; 3.5850x over previous
//
#include <hip/hip_runtime.h>

// ---------------------------------------------------------------------------
// GAT (heads=1) x2 layers x2 branches + FC head, fp32.
// R2: CSR-by-dst aggregation (no float atomics). Per-node fused softmax+
// aggregate kernel replaces edge_p/self_init/edge_aggr. Softmax without the
// max pass (shift-invariant; self-loops guarantee nonempty segments).
// ---------------------------------------------------------------------------

// C[M,128] = (relu_in? relu(A) : A)[M,K] @ W[K,128] (+ bias)
__global__ __launch_bounds__(256) void gemm_k(
    const float* __restrict__ A, const float* __restrict__ W,
    const float* __restrict__ bias, float* __restrict__ C,
    int M, int K, int relu_in)
{
  __shared__ float As[64][33];
  __shared__ float Ws[32][128];
  const int tid = threadIdx.x;
  const int bm  = blockIdx.x * 64;
  const int tc  = tid & 15;
  const int tr  = tid >> 4;
  float acc[4][8];
#pragma unroll
  for (int r = 0; r < 4; ++r)
#pragma unroll
    for (int c = 0; c < 8; ++c) acc[r][c] = 0.f;

  for (int k0 = 0; k0 < K; k0 += 32) {
#pragma unroll
    for (int t = 0; t < 2; ++t) {
      int v   = tid + t * 256;
      int row = v >> 3;
      int kq  = (v & 7) * 4;
      float4 av = make_float4(0.f, 0.f, 0.f, 0.f);
      if (bm + row < M)
        av = *reinterpret_cast<const float4*>(A + (size_t)(bm + row) * K + k0 + kq);
      if (relu_in) {
        av.x = fmaxf(av.x, 0.f); av.y = fmaxf(av.y, 0.f);
        av.z = fmaxf(av.z, 0.f); av.w = fmaxf(av.w, 0.f);
      }
      As[row][kq + 0] = av.x; As[row][kq + 1] = av.y;
      As[row][kq + 2] = av.z; As[row][kq + 3] = av.w;
    }
#pragma unroll
    for (int t = 0; t < 4; ++t) {
      int v  = tid + t * 256;
      int kr = v >> 5;
      int nq = (v & 31) * 4;
      *reinterpret_cast<float4*>(&Ws[kr][nq]) =
          *reinterpret_cast<const float4*>(W + (size_t)(k0 + kr) * 128 + nq);
    }
    __syncthreads();
#pragma unroll
    for (int kk = 0; kk < 32; ++kk) {
      float a[4];
#pragma unroll
      for (int r = 0; r < 4; ++r) a[r] = As[tr * 4 + r][kk];
      float4 w0 = *reinterpret_cast<const float4*>(&Ws[kk][tc * 8]);
      float4 w1 = *reinterpret_cast<const float4*>(&Ws[kk][tc * 8 + 4]);
      float w[8] = {w0.x, w0.y, w0.z, w0.w, w1.x, w1.y, w1.z, w1.w};
#pragma unroll
      for (int r = 0; r < 4; ++r)
#pragma unroll
        for (int c = 0; c < 8; ++c) acc[r][c] += a[r] * w[c];
    }
    __syncthreads();
  }
#pragma unroll
  for (int r = 0; r < 4; ++r) {
    int row = bm + tr * 4 + r;
    if (row >= M) continue;
    float b[8] = {0.f,0.f,0.f,0.f,0.f,0.f,0.f,0.f};
    if (bias) {
#pragma unroll
      for (int c = 0; c < 8; ++c) b[c] = bias[tc * 8 + c];
    }
    float4 o0 = make_float4(acc[r][0] + b[0], acc[r][1] + b[1], acc[r][2] + b[2], acc[r][3] + b[3]);
    float4 o1 = make_float4(acc[r][4] + b[4], acc[r][5] + b[5], acc[r][6] + b[6], acc[r][7] + b[7]);
    *reinterpret_cast<float4*>(C + (size_t)row * 128 + tc * 8)     = o0;
    *reinterpret_cast<float4*>(C + (size_t)row * 128 + tc * 8 + 4) = o1;
  }
}

// es[i] = h[i,:]·a_src ; ed[i] = h[i,:]·a_dst    (one wave per node)
__global__ __launch_bounds__(256) void attn_k(
    const float* __restrict__ h, const float* __restrict__ a_s,
    const float* __restrict__ a_d, float* __restrict__ es, float* __restrict__ ed, int N)
{
  int wave = (blockIdx.x * 256 + threadIdx.x) >> 6;
  int lane = threadIdx.x & 63;
  if (wave >= N) return;
  const float* hr = h + (size_t)wave * 128;
  float h0 = hr[lane], h1 = hr[lane + 64];
  float s = h0 * a_s[lane] + h1 * a_s[lane + 64];
  float d = h0 * a_d[lane] + h1 * a_d[lane + 64];
#pragma unroll
  for (int off = 32; off > 0; off >>= 1) {
    s += __shfl_down(s, off, 64);
    d += __shfl_down(d, off, 64);
  }
  if (lane == 0) { es[wave] = s; ed[wave] = d; }
}

// ---------------- CSR build (by dst, self-loop at slot off[i]) ----------------

__global__ __launch_bounds__(256) void deg_init_k(int* __restrict__ deg, int* __restrict__ off, int N, int total)
{
  int i = blockIdx.x * 256 + threadIdx.x;
  if (i < N) deg[i] = 1;                 // self loop
  if (i == 0) off[N] = total;            // off[N] never touched by scan
}

__global__ __launch_bounds__(256) void deg_k(const int* __restrict__ dst, int* __restrict__ deg, int E)
{
  int e = blockIdx.x * 256 + threadIdx.x;
  if (e < E) atomicAdd(&deg[dst[e]], 1);
}

// exclusive scan, 1024 elements per block (4/thread)
__global__ __launch_bounds__(256) void scan1_k(
    const int* __restrict__ deg, int* __restrict__ off, int* __restrict__ bsum, int N)
{
  __shared__ int ts[256];
  int base = blockIdx.x * 1024 + threadIdx.x * 4;
  int v[4]; int s = 0;
#pragma unroll
  for (int t = 0; t < 4; ++t) { v[t] = (base + t < N) ? deg[base + t] : 0; s += v[t]; }
  ts[threadIdx.x] = s;
  __syncthreads();
  int mine = s;
#pragma unroll
  for (int o = 1; o < 256; o <<= 1) {
    int x = (threadIdx.x >= o) ? ts[threadIdx.x - o] : 0;
    __syncthreads();
    ts[threadIdx.x] += x;
    __syncthreads();
  }
  int run = ts[threadIdx.x] - mine;      // exclusive prefix within block
#pragma unroll
  for (int t = 0; t < 4; ++t) {
    if (base + t < N) off[base + t] = run;
    run += v[t];
  }
  if (threadIdx.x == 255) bsum[blockIdx.x] = ts[255];
}

__global__ __launch_bounds__(256) void scan2_k(int* __restrict__ bsum, int nb)
{
  __shared__ int ts[256];
  int v = (threadIdx.x < nb) ? bsum[threadIdx.x] : 0;
  ts[threadIdx.x] = v;
  __syncthreads();
  int mine = v;
#pragma unroll
  for (int o = 1; o < 256; o <<= 1) {
    int x = (threadIdx.x >= o) ? ts[threadIdx.x - o] : 0;
    __syncthreads();
    ts[threadIdx.x] += x;
    __syncthreads();
  }
  if (threadIdx.x < nb) bsum[threadIdx.x] = ts[threadIdx.x] - mine;
}

__global__ __launch_bounds__(256) void scan3_k(int* __restrict__ off, const int* __restrict__ bsum, int N)
{
  int i = blockIdx.x * 256 + threadIdx.x;
  if (i < N) off[i] += bsum[i >> 10];
}

__global__ __launch_bounds__(256) void fill_self_k(
    const int* __restrict__ off, int* __restrict__ srcs, int* __restrict__ cur, int N)
{
  int i = blockIdx.x * 256 + threadIdx.x;
  if (i < N) { srcs[off[i]] = i; cur[i] = 1; }
}

__global__ __launch_bounds__(256) void fill_edge_k(
    const int* __restrict__ src, const int* __restrict__ dst,
    const int* __restrict__ off, int* __restrict__ cur, int* __restrict__ srcs, int E)
{
  int e = blockIdx.x * 256 + threadIdx.x;
  if (e < E) {
    int d = dst[e];
    int j = off[d] + atomicAdd(&cur[d], 1);
    srcs[j] = src[e];
  }
}

// ---------------- fused per-node softmax + aggregate (one wave per node) -----

__global__ __launch_bounds__(256) void gat_aggr_k(
    const int* __restrict__ off, const int* __restrict__ srcs,
    const float* __restrict__ es, const float* __restrict__ ed,
    const float* __restrict__ h, const float* __restrict__ bias,
    float* __restrict__ out, int N)
{
  int w    = (blockIdx.x * 256 + threadIdx.x) >> 6;
  int lane = threadIdx.x & 63;
  if (w >= N) return;
  int b  = off[w];
  int e2 = off[w + 1];
  float edv = ed[w];
  float ax = 0.f, ay = 0.f, denom = 0.f;
  for (int j = b; j < e2; ++j) {
    int s = srcs[j];
    float l = es[s] + edv;
    l = (l > 0.f) ? l : 0.2f * l;
    float p = expf(l);
    denom += p;
    float2 hv = *reinterpret_cast<const float2*>(h + (size_t)s * 128 + lane * 2);
    ax += p * hv.x;
    ay += p * hv.y;
  }
  float inv = 1.f / denom;
  float2 o = make_float2(ax * inv + bias[lane * 2], ay * inv + bias[lane * 2 + 1]);
  *reinterpret_cast<float2*>(out + (size_t)w * 128 + lane * 2) = o;
}

// fcbuf[i, 0:128] = relu(hx[idx[i]]), [128:256] = relu(hy[idx[i]])
__global__ __launch_bounds__(256) void gather_k(
    const int* __restrict__ idx, const float* __restrict__ hx,
    const float* __restrict__ hy, float* __restrict__ outb, int M)
{
  int t = blockIdx.x * 256 + threadIdx.x;
  if (t >= M * 256) return;
  int i = t >> 8, c = t & 255;
  int r = idx[i];
  float v = (c < 128) ? hx[(size_t)r * 128 + c] : hy[(size_t)r * 128 + (c - 128)];
  outb[t] = fmaxf(v, 0.f);
}

// out[i, 0:64] = relu(fc[i,:]) @ Wout[128,64] + bout   (one wave per row)
__global__ __launch_bounds__(256) void head_k(
    const float* __restrict__ fc, const float* __restrict__ Wout,
    const float* __restrict__ bout, float* __restrict__ out, int M)
{
  __shared__ float rowbuf[4][128];
  int widx = threadIdx.x >> 6;
  int lane = threadIdx.x & 63;
  int i = blockIdx.x * 4 + widx;
  if (i >= M) return;
  const float* fr = fc + (size_t)i * 128;
  rowbuf[widx][lane]      = fmaxf(fr[lane], 0.f);
  rowbuf[widx][lane + 64] = fmaxf(fr[lane + 64], 0.f);
  float acc = bout[lane];
#pragma unroll 8
  for (int k = 0; k < 128; ++k) acc += rowbuf[widx][k] * Wout[k * 64 + lane];
  out[(size_t)i * 64 + lane] = acc;
}

// ---------------------------------------------------------------------------

static void build_csr(const int* src, const int* dst, int E, int N,
                      int* off, int* srcs, int* cur, int* bsum, hipStream_t stream)
{
  const int nb = (N + 1023) / 1024;
  deg_init_k<<<dim3((N + 255) / 256), 256, 0, stream>>>(cur, off, N, E + N);  // cur as deg
  deg_k<<<dim3((E + 255) / 256), 256, 0, stream>>>(dst, cur, E);
  scan1_k<<<dim3(nb), 256, 0, stream>>>(cur, off, bsum, N);
  scan2_k<<<dim3(1), 256, 0, stream>>>(bsum, nb);
  scan3_k<<<dim3((N + 255) / 256), 256, 0, stream>>>(off, bsum, N);
  fill_self_k<<<dim3((N + 255) / 256), 256, 0, stream>>>(off, srcs, cur, N);
  fill_edge_k<<<dim3((E + 255) / 256), 256, 0, stream>>>(src, dst, off, cur, srcs, E);
}

static void run_gat_layer(const float* in, int relu_in, const float* W,
                          const float* a_s, const float* a_d, const float* b,
                          const int* off, const int* srcs, int N,
                          float* h, float* es, float* ed, float* out, hipStream_t stream)
{
  gemm_k<<<dim3((N + 63) / 64), 256, 0, stream>>>(in, W, nullptr, h, N, 128, relu_in);
  attn_k<<<dim3((N + 3) / 4), 256, 0, stream>>>(h, a_s, a_d, es, ed, N);
  gat_aggr_k<<<dim3((N + 3) / 4), 256, 0, stream>>>(off, srcs, es, ed, h, b, out, N);
}

extern "C" void kernel_launch(void* const* d_in, const int* in_sizes, int n_in,
                              void* d_out, int out_size, void* d_ws, size_t ws_size,
                              hipStream_t stream)
{
  const float* x    = (const float*)d_in[0];
  const int*   eix  = (const int*)d_in[1];
  const int*   eiy  = (const int*)d_in[2];
  const int*   idx  = (const int*)d_in[3];
  const float* Wx1  = (const float*)d_in[4];
  const float* asx1 = (const float*)d_in[5];
  const float* adx1 = (const float*)d_in[6];
  const float* bx1  = (const float*)d_in[7];
  const float* Wx2  = (const float*)d_in[8];
  const float* asx2 = (const float*)d_in[9];
  const float* adx2 = (const float*)d_in[10];
  const float* bx2  = (const float*)d_in[11];
  const float* Wy1  = (const float*)d_in[12];
  const float* asy1 = (const float*)d_in[13];
  const float* ady1 = (const float*)d_in[14];
  const float* by1  = (const float*)d_in[15];
  const float* Wy2  = (const float*)d_in[16];
  const float* asy2 = (const float*)d_in[17];
  const float* ady2 = (const float*)d_in[18];
  const float* by2  = (const float*)d_in[19];
  const float* Wfc  = (const float*)d_in[20];
  const float* bfc  = (const float*)d_in[21];
  const float* Wout = (const float*)d_in[22];
  const float* bout = (const float*)d_in[23];

  const int N    = in_sizes[0] / 128;   // 50000
  const int E    = in_sizes[1] / 2;     // 600000
  const int Midx = in_sizes[3];         // 10000

  const int* srcx = eix;
  const int* dstx = eix + E;
  const int* srcy = eiy;
  const int* dsty = eiy + E;

  // workspace layout
  char* wsb = (char*)d_ws;
  const size_t NB = (size_t)N * 128 * 4;          // 25.6 MB
  float* hbuf  = (float*)(wsb);
  float* inter = (float*)(wsb + NB);
  float* hx    = (float*)(wsb + 2 * NB);
  float* hy    = (float*)(wsb + 3 * NB);
  char*  p     = wsb + 4 * NB;
  float* es    = (float*)p;            p += (size_t)N * 4;
  float* ed    = (float*)p;            p += (size_t)N * 4;
  int*   offx  = (int*)p;              p += (size_t)(N + 1) * 4;
  int*   offy  = (int*)p;              p += (size_t)(N + 1) * 4;
  int*   cur   = (int*)p;              p += (size_t)N * 4;       // deg/cursor scratch
  int*   bsum  = (int*)p;              p += 256 * 4;
  int*   srcxs = (int*)p;              p += (size_t)(E + N) * 4;
  int*   srcys = (int*)p;              p += (size_t)(E + N) * 4;

  build_csr(srcx, dstx, E, N, offx, srcxs, cur, bsum, stream);
  build_csr(srcy, dsty, E, N, offy, srcys, cur, bsum, stream);

  // x branch
  run_gat_layer(x,     0, Wx1, asx1, adx1, bx1, offx, srcxs, N, hbuf, es, ed, inter, stream);
  run_gat_layer(inter, 1, Wx2, asx2, adx2, bx2, offx, srcxs, N, hbuf, es, ed, hx,    stream);
  // y branch
  run_gat_layer(x,     0, Wy1, asy1, ady1, by1, offy, srcys, N, hbuf, es, ed, inter, stream);
  run_gat_layer(inter, 1, Wy2, asy2, ady2, by2, offy, srcys, N, hbuf, es, ed, hy,    stream);

  // head: only the 10000 indexed rows
  float* fcbuf = hbuf;            // 10000 x 256 (reuse)
  float* fcout = inter;           // 10000 x 128 (reuse)
  gather_k<<<dim3((Midx * 256 + 255) / 256), 256, 0, stream>>>(idx, hx, hy, fcbuf, Midx);
  gemm_k<<<dim3((Midx + 63) / 64), 256, 0, stream>>>(fcbuf, Wfc, bfc, fcout, Midx, 256, 0);
  head_k<<<dim3((Midx + 3) / 4), 256, 0, stream>>>(fcout, Wout, bout, (float*)d_out, Midx);
}

// Round 3
// 521.166 us; speedup vs baseline: 4.5827x; 1.2783x over previous
//
#include <hip/hip_runtime.h>

// ---------------------------------------------------------------------------
// GAT (heads=1) x2 layers x2 branches + FC head, fp32.
// R3: (a) attn (es/ed) fused into GEMM epilogue; (b) gat_aggr restructured:
// per-64-edge chunk, lanes compute p in parallel (coalesced srcs load, one
// expf per edge), then 8-deep-pipelined h-row gather via register shuffles.
// Softmax without the max pass (shift-invariant; self-loops guarantee
// nonempty segments; |logits| small).
// ---------------------------------------------------------------------------

// C[M,128] = (relu_in? relu(A) : A)[M,K] @ W[K,128] (+ bias)
// If a_s != nullptr: also es[row] = C_row · a_s, ed[row] = C_row · a_d.
__global__ __launch_bounds__(256) void gemm_k(
    const float* __restrict__ A, const float* __restrict__ W,
    const float* __restrict__ bias,
    const float* __restrict__ a_s, const float* __restrict__ a_d,
    float* __restrict__ C, float* __restrict__ es, float* __restrict__ ed,
    int M, int K, int relu_in)
{
  __shared__ float As[64][33];
  __shared__ float Ws[32][128];
  const int tid = threadIdx.x;
  const int bm  = blockIdx.x * 64;
  const int tc  = tid & 15;
  const int tr  = tid >> 4;
  float acc[4][8];
#pragma unroll
  for (int r = 0; r < 4; ++r)
#pragma unroll
    for (int c = 0; c < 8; ++c) acc[r][c] = 0.f;

  for (int k0 = 0; k0 < K; k0 += 32) {
#pragma unroll
    for (int t = 0; t < 2; ++t) {
      int v   = tid + t * 256;
      int row = v >> 3;
      int kq  = (v & 7) * 4;
      float4 av = make_float4(0.f, 0.f, 0.f, 0.f);
      if (bm + row < M)
        av = *reinterpret_cast<const float4*>(A + (size_t)(bm + row) * K + k0 + kq);
      if (relu_in) {
        av.x = fmaxf(av.x, 0.f); av.y = fmaxf(av.y, 0.f);
        av.z = fmaxf(av.z, 0.f); av.w = fmaxf(av.w, 0.f);
      }
      As[row][kq + 0] = av.x; As[row][kq + 1] = av.y;
      As[row][kq + 2] = av.z; As[row][kq + 3] = av.w;
    }
#pragma unroll
    for (int t = 0; t < 4; ++t) {
      int v  = tid + t * 256;
      int kr = v >> 5;
      int nq = (v & 31) * 4;
      *reinterpret_cast<float4*>(&Ws[kr][nq]) =
          *reinterpret_cast<const float4*>(W + (size_t)(k0 + kr) * 128 + nq);
    }
    __syncthreads();
#pragma unroll
    for (int kk = 0; kk < 32; ++kk) {
      float a[4];
#pragma unroll
      for (int r = 0; r < 4; ++r) a[r] = As[tr * 4 + r][kk];
      float4 w0 = *reinterpret_cast<const float4*>(&Ws[kk][tc * 8]);
      float4 w1 = *reinterpret_cast<const float4*>(&Ws[kk][tc * 8 + 4]);
      float w[8] = {w0.x, w0.y, w0.z, w0.w, w1.x, w1.y, w1.z, w1.w};
#pragma unroll
      for (int r = 0; r < 4; ++r)
#pragma unroll
        for (int c = 0; c < 8; ++c) acc[r][c] += a[r] * w[c];
    }
    __syncthreads();
  }

  // C write
#pragma unroll
  for (int r = 0; r < 4; ++r) {
    int row = bm + tr * 4 + r;
    if (row >= M) continue;
    float b[8] = {0.f,0.f,0.f,0.f,0.f,0.f,0.f,0.f};
    if (bias) {
#pragma unroll
      for (int c = 0; c < 8; ++c) b[c] = bias[tc * 8 + c];
    }
    float4 o0 = make_float4(acc[r][0] + b[0], acc[r][1] + b[1], acc[r][2] + b[2], acc[r][3] + b[3]);
    float4 o1 = make_float4(acc[r][4] + b[4], acc[r][5] + b[5], acc[r][6] + b[6], acc[r][7] + b[7]);
    *reinterpret_cast<float4*>(C + (size_t)row * 128 + tc * 8)     = o0;
    *reinterpret_cast<float4*>(C + (size_t)row * 128 + tc * 8 + 4) = o1;
  }

  // fused attn epilogue: es/ed per row (reduce over the 16 col-groups; the
  // 16 threads sharing tr are 16 consecutive lanes of one wave)
  if (a_s) {
    float asv[8], adv[8];
#pragma unroll
    for (int c = 0; c < 8; ++c) { asv[c] = a_s[tc * 8 + c]; adv[c] = a_d[tc * 8 + c]; }
#pragma unroll
    for (int r = 0; r < 4; ++r) {
      float ps = 0.f, pd = 0.f;
#pragma unroll
      for (int c = 0; c < 8; ++c) { ps += acc[r][c] * asv[c]; pd += acc[r][c] * adv[c]; }
#pragma unroll
      for (int o = 1; o < 16; o <<= 1) {
        ps += __shfl_xor(ps, o, 64);
        pd += __shfl_xor(pd, o, 64);
      }
      int row = bm + tr * 4 + r;
      if (tc == 0 && row < M) { es[row] = ps; ed[row] = pd; }
    }
  }
}

// ---------------- CSR build (by dst, self-loop at slot off[i]) ----------------

__global__ __launch_bounds__(256) void deg_init_k(int* __restrict__ deg, int* __restrict__ off, int N, int total)
{
  int i = blockIdx.x * 256 + threadIdx.x;
  if (i < N) deg[i] = 1;                 // self loop
  if (i == 0) off[N] = total;
}

__global__ __launch_bounds__(256) void deg_k(const int* __restrict__ dst, int* __restrict__ deg, int E)
{
  int e = blockIdx.x * 256 + threadIdx.x;
  if (e < E) atomicAdd(&deg[dst[e]], 1);
}

// exclusive scan, 1024 elements per block (4/thread)
__global__ __launch_bounds__(256) void scan1_k(
    const int* __restrict__ deg, int* __restrict__ off, int* __restrict__ bsum, int N)
{
  __shared__ int ts[256];
  int base = blockIdx.x * 1024 + threadIdx.x * 4;
  int v[4]; int s = 0;
#pragma unroll
  for (int t = 0; t < 4; ++t) { v[t] = (base + t < N) ? deg[base + t] : 0; s += v[t]; }
  ts[threadIdx.x] = s;
  __syncthreads();
  int mine = s;
#pragma unroll
  for (int o = 1; o < 256; o <<= 1) {
    int x = (threadIdx.x >= o) ? ts[threadIdx.x - o] : 0;
    __syncthreads();
    ts[threadIdx.x] += x;
    __syncthreads();
  }
  int run = ts[threadIdx.x] - mine;
#pragma unroll
  for (int t = 0; t < 4; ++t) {
    if (base + t < N) off[base + t] = run;
    run += v[t];
  }
  if (threadIdx.x == 255) bsum[blockIdx.x] = ts[255];
}

__global__ __launch_bounds__(256) void scan2_k(int* __restrict__ bsum, int nb)
{
  __shared__ int ts[256];
  int v = (threadIdx.x < nb) ? bsum[threadIdx.x] : 0;
  ts[threadIdx.x] = v;
  __syncthreads();
  int mine = v;
#pragma unroll
  for (int o = 1; o < 256; o <<= 1) {
    int x = (threadIdx.x >= o) ? ts[threadIdx.x - o] : 0;
    __syncthreads();
    ts[threadIdx.x] += x;
    __syncthreads();
  }
  if (threadIdx.x < nb) bsum[threadIdx.x] = ts[threadIdx.x] - mine;
}

__global__ __launch_bounds__(256) void scan3_k(int* __restrict__ off, const int* __restrict__ bsum, int N)
{
  int i = blockIdx.x * 256 + threadIdx.x;
  if (i < N) off[i] += bsum[i >> 10];
}

__global__ __launch_bounds__(256) void fill_self_k(
    const int* __restrict__ off, int* __restrict__ srcs, int* __restrict__ cur, int N)
{
  int i = blockIdx.x * 256 + threadIdx.x;
  if (i < N) { srcs[off[i]] = i; cur[i] = 1; }
}

__global__ __launch_bounds__(256) void fill_edge_k(
    const int* __restrict__ src, const int* __restrict__ dst,
    const int* __restrict__ off, int* __restrict__ cur, int* __restrict__ srcs, int E)
{
  int e = blockIdx.x * 256 + threadIdx.x;
  if (e < E) {
    int d = dst[e];
    int j = off[d] + atomicAdd(&cur[d], 1);
    srcs[j] = src[e];
  }
}

// ---------------- fused per-node softmax + aggregate (one wave per node) -----
// Per 64-edge chunk: lane i computes p_i in parallel (coalesced srcs read,
// one expf per edge); aggregation pulls (s,p) via shfl, 8 h-row loads in
// flight per step.
__global__ __launch_bounds__(256) void gat_aggr_k(
    const int* __restrict__ off, const int* __restrict__ srcs,
    const float* __restrict__ es, const float* __restrict__ ed,
    const float* __restrict__ h, const float* __restrict__ bias,
    float* __restrict__ out, int N)
{
  int w    = (blockIdx.x * 256 + threadIdx.x) >> 6;
  int lane = threadIdx.x & 63;
  if (w >= N) return;
  int b  = off[w];
  int e2 = off[w + 1];
  float edv = ed[w];
  float ax = 0.f, ay = 0.f, dsum = 0.f;

  for (int c0 = b; c0 < e2; c0 += 64) {
    int nc = e2 - c0; if (nc > 64) nc = 64;
    int  sl = srcs[c0 + (lane < nc ? lane : 0)];
    float pl = 0.f;
    if (lane < nc) {
      float l = es[sl] + edv;
      l = (l > 0.f) ? l : 0.2f * l;
      pl = expf(l);
    }
    dsum += pl;

    for (int e = 0; e < nc; e += 8) {
      float2 hv[8]; float pp[8];
#pragma unroll
      for (int k = 0; k < 8; ++k) {
        int  ok  = (e + k) < nc;
        int  idx = ok ? (e + k) : 0;
        int  s   = __shfl(sl, idx, 64);
        pp[k]    = ok ? __shfl(pl, idx, 64) : 0.f;
        hv[k]    = *reinterpret_cast<const float2*>(h + (size_t)s * 128 + lane * 2);
      }
#pragma unroll
      for (int k = 0; k < 8; ++k) { ax += pp[k] * hv[k].x; ay += pp[k] * hv[k].y; }
    }
  }

#pragma unroll
  for (int o = 32; o > 0; o >>= 1) dsum += __shfl_xor(dsum, o, 64);
  float inv = 1.f / dsum;
  float2 o2 = make_float2(ax * inv + bias[lane * 2], ay * inv + bias[lane * 2 + 1]);
  *reinterpret_cast<float2*>(out + (size_t)w * 128 + lane * 2) = o2;
}

// fcbuf[i, 0:128] = relu(hx[idx[i]]), [128:256] = relu(hy[idx[i]])
__global__ __launch_bounds__(256) void gather_k(
    const int* __restrict__ idx, const float* __restrict__ hx,
    const float* __restrict__ hy, float* __restrict__ outb, int M)
{
  int t = blockIdx.x * 256 + threadIdx.x;
  if (t >= M * 256) return;
  int i = t >> 8, c = t & 255;
  int r = idx[i];
  float v = (c < 128) ? hx[(size_t)r * 128 + c] : hy[(size_t)r * 128 + (c - 128)];
  outb[t] = fmaxf(v, 0.f);
}

// out[i, 0:64] = relu(fc[i,:]) @ Wout[128,64] + bout   (one wave per row)
__global__ __launch_bounds__(256) void head_k(
    const float* __restrict__ fc, const float* __restrict__ Wout,
    const float* __restrict__ bout, float* __restrict__ out, int M)
{
  __shared__ float rowbuf[4][128];
  int widx = threadIdx.x >> 6;
  int lane = threadIdx.x & 63;
  int i = blockIdx.x * 4 + widx;
  if (i >= M) return;
  const float* fr = fc + (size_t)i * 128;
  rowbuf[widx][lane]      = fmaxf(fr[lane], 0.f);
  rowbuf[widx][lane + 64] = fmaxf(fr[lane + 64], 0.f);
  float acc = bout[lane];
#pragma unroll 8
  for (int k = 0; k < 128; ++k) acc += rowbuf[widx][k] * Wout[k * 64 + lane];
  out[(size_t)i * 64 + lane] = acc;
}

// ---------------------------------------------------------------------------

static void build_csr(const int* src, const int* dst, int E, int N,
                      int* off, int* srcs, int* cur, int* bsum, hipStream_t stream)
{
  const int nb = (N + 1023) / 1024;
  deg_init_k<<<dim3((N + 255) / 256), 256, 0, stream>>>(cur, off, N, E + N);
  deg_k<<<dim3((E + 255) / 256), 256, 0, stream>>>(dst, cur, E);
  scan1_k<<<dim3(nb), 256, 0, stream>>>(cur, off, bsum, N);
  scan2_k<<<dim3(1), 256, 0, stream>>>(bsum, nb);
  scan3_k<<<dim3((N + 255) / 256), 256, 0, stream>>>(off, bsum, N);
  fill_self_k<<<dim3((N + 255) / 256), 256, 0, stream>>>(off, srcs, cur, N);
  fill_edge_k<<<dim3((E + 255) / 256), 256, 0, stream>>>(src, dst, off, cur, srcs, E);
}

static void run_gat_layer(const float* in, int relu_in, const float* W,
                          const float* a_s, const float* a_d, const float* b,
                          const int* off, const int* srcs, int N,
                          float* h, float* es, float* ed, float* out, hipStream_t stream)
{
  gemm_k<<<dim3((N + 63) / 64), 256, 0, stream>>>(in, W, nullptr, a_s, a_d, h, es, ed, N, 128, relu_in);
  gat_aggr_k<<<dim3((N + 3) / 4), 256, 0, stream>>>(off, srcs, es, ed, h, b, out, N);
}

extern "C" void kernel_launch(void* const* d_in, const int* in_sizes, int n_in,
                              void* d_out, int out_size, void* d_ws, size_t ws_size,
                              hipStream_t stream)
{
  const float* x    = (const float*)d_in[0];
  const int*   eix  = (const int*)d_in[1];
  const int*   eiy  = (const int*)d_in[2];
  const int*   idx  = (const int*)d_in[3];
  const float* Wx1  = (const float*)d_in[4];
  const float* asx1 = (const float*)d_in[5];
  const float* adx1 = (const float*)d_in[6];
  const float* bx1  = (const float*)d_in[7];
  const float* Wx2  = (const float*)d_in[8];
  const float* asx2 = (const float*)d_in[9];
  const float* adx2 = (const float*)d_in[10];
  const float* bx2  = (const float*)d_in[11];
  const float* Wy1  = (const float*)d_in[12];
  const float* asy1 = (const float*)d_in[13];
  const float* ady1 = (const float*)d_in[14];
  const float* by1  = (const float*)d_in[15];
  const float* Wy2  = (const float*)d_in[16];
  const float* asy2 = (const float*)d_in[17];
  const float* ady2 = (const float*)d_in[18];
  const float* by2  = (const float*)d_in[19];
  const float* Wfc  = (const float*)d_in[20];
  const float* bfc  = (const float*)d_in[21];
  const float* Wout = (const float*)d_in[22];
  const float* bout = (const float*)d_in[23];

  const int N    = in_sizes[0] / 128;   // 50000
  const int E    = in_sizes[1] / 2;     // 600000
  const int Midx = in_sizes[3];         // 10000

  const int* srcx = eix;
  const int* dstx = eix + E;
  const int* srcy = eiy;
  const int* dsty = eiy + E;

  // workspace layout
  char* wsb = (char*)d_ws;
  const size_t NB = (size_t)N * 128 * 4;          // 25.6 MB
  float* hbuf  = (float*)(wsb);
  float* inter = (float*)(wsb + NB);
  float* hx    = (float*)(wsb + 2 * NB);
  float* hy    = (float*)(wsb + 3 * NB);
  char*  p     = wsb + 4 * NB;
  float* es    = (float*)p;            p += (size_t)N * 4;
  float* ed    = (float*)p;            p += (size_t)N * 4;
  int*   offx  = (int*)p;              p += (size_t)(N + 1) * 4;
  int*   offy  = (int*)p;              p += (size_t)(N + 1) * 4;
  int*   cur   = (int*)p;              p += (size_t)N * 4;
  int*   bsum  = (int*)p;              p += 256 * 4;
  int*   srcxs = (int*)p;              p += (size_t)(E + N) * 4;
  int*   srcys = (int*)p;              p += (size_t)(E + N) * 4;

  build_csr(srcx, dstx, E, N, offx, srcxs, cur, bsum, stream);
  build_csr(srcy, dsty, E, N, offy, srcys, cur, bsum, stream);

  // x branch
  run_gat_layer(x,     0, Wx1, asx1, adx1, bx1, offx, srcxs, N, hbuf, es, ed, inter, stream);
  run_gat_layer(inter, 1, Wx2, asx2, adx2, bx2, offx, srcxs, N, hbuf, es, ed, hx,    stream);
  // y branch
  run_gat_layer(x,     0, Wy1, asy1, ady1, by1, offy, srcys, N, hbuf, es, ed, inter, stream);
  run_gat_layer(inter, 1, Wy2, asy2, ady2, by2, offy, srcys, N, hbuf, es, ed, hy,    stream);

  // head: only the 10000 indexed rows
  float* fcbuf = hbuf;            // 10000 x 256 (reuse)
  float* fcout = inter;           // 10000 x 128 (reuse)
  gather_k<<<dim3((Midx * 256 + 255) / 256), 256, 0, stream>>>(idx, hx, hy, fcbuf, Midx);
  gemm_k<<<dim3((Midx + 63) / 64), 256, 0, stream>>>(fcbuf, Wfc, bfc, nullptr, nullptr, fcout, nullptr, nullptr, Midx, 256, 0);
  head_k<<<dim3((Midx + 3) / 4), 256, 0, stream>>>(fcout, Wout, bout, (float*)d_out, Midx);
}